// Round 1
// baseline (430.111 us; speedup 1.0000x reference)
//
#include <hip/hip_runtime.h>

typedef unsigned short u16;
typedef __attribute__((ext_vector_type(8))) short bf16x8;
typedef __attribute__((ext_vector_type(4))) float f32x4;

__device__ __forceinline__ u16 f2bf(float f) {
  union { float f; unsigned u; } v; v.f = f;
  unsigned r = v.u + 0x7fffu + ((v.u >> 16) & 1u);
  return (u16)(r >> 16);
}
__device__ __forceinline__ float bf2f(u16 h) {
  union { unsigned u; float f; } v; v.u = ((unsigned)h) << 16;
  return v.f;
}

// ---------------- fp32 -> bf16 convert (vectorized) ----------------
__global__ __launch_bounds__(256) void k_f32_to_bf16(const float* __restrict__ in,
                                                     u16* __restrict__ out, int n4) {
  int i = blockIdx.x * 256 + threadIdx.x;
  if (i < n4) {
    float4 v = ((const float4*)in)[i];
    u16 o0 = f2bf(v.x), o1 = f2bf(v.y), o2 = f2bf(v.z), o3 = f2bf(v.w);
    bf16x8 dummy; (void)dummy;
    ushort4 o; o.x = o0; o.y = o1; o.z = o2; o.w = o3;
    ((ushort4*)out)[i] = o;
  }
}

// ---------------- fp32 [R][C] -> bf16 [C][R] transpose ----------------
__global__ __launch_bounds__(256) void k_transpose_bf16(const float* __restrict__ in,
                                                        u16* __restrict__ out,
                                                        int R, int C) {
  __shared__ float tile[32][33];
  int bx = blockIdx.x * 32;  // col base in 'in'
  int by = blockIdx.y * 32;  // row base in 'in'
  int tx = threadIdx.x, ty = threadIdx.y;  // (32, 8)
#pragma unroll
  for (int j = 0; j < 32; j += 8)
    tile[ty + j][tx] = in[(size_t)(by + ty + j) * C + bx + tx];
  __syncthreads();
#pragma unroll
  for (int j = 0; j < 32; j += 8)
    out[(size_t)(bx + ty + j) * R + by + tx] = f2bf(tile[tx][ty + j]);
}

#define GAS(p) ((const __attribute__((address_space(1))) void*)(p))
#define LAS(p) ((__attribute__((address_space(3))) void*)(p))

// ---------------- QKV GEMM: [8192,768] x [768,2304] + bias, scatter to Q/K/V ----------------
__global__ __launch_bounds__(256) void k_gemm_qkv(
    const u16* __restrict__ A,   // xb [8192][768]
    const u16* __restrict__ Bt,  // wt  [2304][768]  (qkv_w transposed)
    const float* __restrict__ bias,
    u16* __restrict__ Qb, u16* __restrict__ Kb, u16* __restrict__ Vb) {
  const int K = 768;
  __shared__ u16 Al[128 * 64];
  __shared__ u16 Bl[128 * 64];
  int tn0 = blockIdx.x * 128, tm0 = blockIdx.y * 128;
  int tid = threadIdx.x, w = tid >> 6, lane = tid & 63;
  int l16 = lane & 15, lg = lane >> 4;
  int wm = (w >> 1) * 64, wn = (w & 1) * 64;
  f32x4 acc[4][4];
#pragma unroll
  for (int fm = 0; fm < 4; ++fm)
#pragma unroll
    for (int fn = 0; fn < 4; ++fn) acc[fm][fn] = (f32x4){0.f, 0.f, 0.f, 0.f};
  int srow = w * 32 + (lane >> 3);
  int scol = (lane & 7) * 8;
  for (int k0 = 0; k0 < K; k0 += 64) {
#pragma unroll
    for (int i = 0; i < 4; ++i) {
      __builtin_amdgcn_global_load_lds(GAS(A + (size_t)(tm0 + srow + i * 8) * K + k0 + scol),
                                       LAS((char*)Al + w * 4096 + i * 1024 + lane * 16), 16, 0, 0);
      __builtin_amdgcn_global_load_lds(GAS(Bt + (size_t)(tn0 + srow + i * 8) * K + k0 + scol),
                                       LAS((char*)Bl + w * 4096 + i * 1024 + lane * 16), 16, 0, 0);
    }
    __syncthreads();
#pragma unroll
    for (int ks = 0; ks < 2; ++ks) {
      bf16x8 af[4], bv[4];
#pragma unroll
      for (int f = 0; f < 4; ++f)
        af[f] = *(const bf16x8*)&Al[(wm + f * 16 + l16) * 64 + lg * 8 + ks * 32];
#pragma unroll
      for (int f = 0; f < 4; ++f)
        bv[f] = *(const bf16x8*)&Bl[(wn + f * 16 + l16) * 64 + lg * 8 + ks * 32];
#pragma unroll
      for (int fm = 0; fm < 4; ++fm)
#pragma unroll
        for (int fn = 0; fn < 4; ++fn)
          acc[fm][fn] = __builtin_amdgcn_mfma_f32_16x16x32_bf16(af[fm], bv[fn], acc[fm][fn], 0, 0, 0);
    }
    __syncthreads();
  }
  // epilogue: n = tn0 + wn + fn*16 + l16 ; part uniform per block (768 = 6*128)
  int part = tn0 / 768;
  u16* dst = part == 0 ? Qb : (part == 1 ? Kb : Vb);
#pragma unroll
  for (int fn = 0; fn < 4; ++fn) {
    int nn = tn0 + wn + fn * 16 + l16;
    float bvs = bias[nn];
    int np = nn - part * 768;
    int hh = np >> 6, hd = np & 63;
#pragma unroll
    for (int fm = 0; fm < 4; ++fm) {
#pragma unroll
      for (int r = 0; r < 4; ++r) {
        int m = tm0 + wm + fm * 16 + lg * 4 + r;
        int bb = m >> 12, s = m & 4095;
        dst[(((size_t)(bb * 12 + hh)) * 4096 + s) * 64 + hd] = f2bf(acc[fm][fn][r] + bvs);
      }
    }
  }
}

// ---------------- proj GEMM: [8192,768] x [768,768] + bias -> fp32 out ----------------
__global__ __launch_bounds__(256) void k_gemm_proj(
    const u16* __restrict__ A,   // Ob [8192][768]
    const u16* __restrict__ Bt,  // pwt [768][768]
    const float* __restrict__ bias, float* __restrict__ out) {
  const int K = 768;
  __shared__ u16 Al[128 * 64];
  __shared__ u16 Bl[128 * 64];
  int tn0 = blockIdx.x * 128, tm0 = blockIdx.y * 128;
  int tid = threadIdx.x, w = tid >> 6, lane = tid & 63;
  int l16 = lane & 15, lg = lane >> 4;
  int wm = (w >> 1) * 64, wn = (w & 1) * 64;
  f32x4 acc[4][4];
#pragma unroll
  for (int fm = 0; fm < 4; ++fm)
#pragma unroll
    for (int fn = 0; fn < 4; ++fn) acc[fm][fn] = (f32x4){0.f, 0.f, 0.f, 0.f};
  int srow = w * 32 + (lane >> 3);
  int scol = (lane & 7) * 8;
  for (int k0 = 0; k0 < K; k0 += 64) {
#pragma unroll
    for (int i = 0; i < 4; ++i) {
      __builtin_amdgcn_global_load_lds(GAS(A + (size_t)(tm0 + srow + i * 8) * K + k0 + scol),
                                       LAS((char*)Al + w * 4096 + i * 1024 + lane * 16), 16, 0, 0);
      __builtin_amdgcn_global_load_lds(GAS(Bt + (size_t)(tn0 + srow + i * 8) * K + k0 + scol),
                                       LAS((char*)Bl + w * 4096 + i * 1024 + lane * 16), 16, 0, 0);
    }
    __syncthreads();
#pragma unroll
    for (int ks = 0; ks < 2; ++ks) {
      bf16x8 af[4], bv[4];
#pragma unroll
      for (int f = 0; f < 4; ++f)
        af[f] = *(const bf16x8*)&Al[(wm + f * 16 + l16) * 64 + lg * 8 + ks * 32];
#pragma unroll
      for (int f = 0; f < 4; ++f)
        bv[f] = *(const bf16x8*)&Bl[(wn + f * 16 + l16) * 64 + lg * 8 + ks * 32];
#pragma unroll
      for (int fm = 0; fm < 4; ++fm)
#pragma unroll
        for (int fn = 0; fn < 4; ++fn)
          acc[fm][fn] = __builtin_amdgcn_mfma_f32_16x16x32_bf16(af[fm], bv[fn], acc[fm][fn], 0, 0, 0);
    }
    __syncthreads();
  }
#pragma unroll
  for (int fn = 0; fn < 4; ++fn) {
    int nn = tn0 + wn + fn * 16 + l16;
    float bvs = bias[nn];
#pragma unroll
    for (int fm = 0; fm < 4; ++fm) {
#pragma unroll
      for (int r = 0; r < 4; ++r) {
        int m = tm0 + wm + fm * 16 + lg * 4 + r;
        out[(size_t)m * 768 + nn] = acc[fm][fn][r] + bvs;
      }
    }
  }
}

// ---------------- flash attention: per (b,h), QBLK=64 (4 waves x 16 rows), KVBLK=64 ----------------
__global__ __launch_bounds__(256) void k_attn(const u16* __restrict__ Qb,
                                              const u16* __restrict__ Kb,
                                              const u16* __restrict__ Vb,
                                              u16* __restrict__ Ob) {
  const int S = 4096, HD = 64, NH = 12, D = 768;
  __shared__ u16 Kl[64 * 64];       // [sk][hd], XOR-swizzled rows
  __shared__ u16 Vt[64 * 64];       // [hd][sk], XOR-swizzled rows
  __shared__ u16 Pl[4][16 * 64];    // per-wave P [qrow][sk], swizzled

  int bid = blockIdx.x;
  int qb = bid & 63;
  int bh = bid >> 6;  // 0..23, consecutive blocks share (b,h) -> K/V L2 reuse
  int b = bh / NH, h = bh % NH;
  const u16* Qh = Qb + (size_t)bh * S * HD;
  const u16* Kh = Kb + (size_t)bh * S * HD;
  const u16* Vh = Vb + (size_t)bh * S * HD;

  int tid = threadIdx.x, w = tid >> 6, lane = tid & 63;
  int l16 = lane & 15, lg = lane >> 4;

  // Q fragments, pre-scaled by HD^-0.5 = 1/8 (exact in bf16)
  int sq0 = qb * 64 + w * 16;
  bf16x8 qf[2];
#pragma unroll
  for (int ks = 0; ks < 2; ++ks) {
    bf16x8 q = *(const bf16x8*)&Qh[(size_t)(sq0 + l16) * HD + lg * 8 + ks * 32];
#pragma unroll
    for (int j = 0; j < 8; ++j) q[j] = (short)f2bf(bf2f((u16)q[j]) * 0.125f);
    qf[ks] = q;
  }

  f32x4 of[4];
  float m_i[4], l_i[4];
#pragma unroll
  for (int f = 0; f < 4; ++f) of[f] = (f32x4){0.f, 0.f, 0.f, 0.f};
#pragma unroll
  for (int i = 0; i < 4; ++i) { m_i[i] = -1e30f; l_i[i] = 0.f; }

  for (int kv = 0; kv < S / 64; ++kv) {
    // stage K tile (swizzled [sk][hd])
    {
      int sk = tid >> 2, ch = tid & 3;
      const u16* src = &Kh[(size_t)(kv * 64 + sk) * HD + ch * 16];
#pragma unroll
      for (int half = 0; half < 2; ++half) {
        bf16x8 v = *(const bf16x8*)(src + half * 8);
        int e2 = ch * 32 + half * 16;  // byte offset within row
        *(bf16x8*)((char*)Kl + sk * 128 + (e2 ^ ((sk & 7) << 4))) = v;
      }
    }
    // stage V^T tile (swizzled [hd][sk])
    {
      int hd = tid & 63, skg = tid >> 6;
      u16 tmp[16];
#pragma unroll
      for (int j = 0; j < 16; ++j)
        tmp[j] = Vh[(size_t)(kv * 64 + skg * 16 + j) * HD + hd];
#pragma unroll
      for (int half = 0; half < 2; ++half) {
        int e2 = skg * 32 + half * 16;
        *(bf16x8*)((char*)Vt + hd * 128 + (e2 ^ ((hd & 7) << 4))) = *(bf16x8*)&tmp[half * 8];
      }
    }
    __syncthreads();

    // QK^T : S-tile 16 x 64 per wave
    f32x4 sacc[4];
#pragma unroll
    for (int f = 0; f < 4; ++f) sacc[f] = (f32x4){0.f, 0.f, 0.f, 0.f};
#pragma unroll
    for (int ks = 0; ks < 2; ++ks) {
#pragma unroll
      for (int nf = 0; nf < 4; ++nf) {
        int row = l16 + nf * 16;
        bf16x8 kf = *(const bf16x8*)((const char*)Kl + row * 128 +
                                     ((lg * 16 + ks * 64) ^ ((row & 7) << 4)));
        sacc[nf] = __builtin_amdgcn_mfma_f32_16x16x32_bf16(qf[ks], kf, sacc[nf], 0, 0, 0);
      }
    }

    // online softmax (rows: (lg*4 + i), 16 lanes l16 = columns)
    float p[4][4];
#pragma unroll
    for (int i = 0; i < 4; ++i) {
      float mx = fmaxf(fmaxf(sacc[0][i], sacc[1][i]), fmaxf(sacc[2][i], sacc[3][i]));
#pragma unroll
      for (int off = 1; off < 16; off <<= 1) mx = fmaxf(mx, __shfl_xor(mx, off, 64));
      float mnew = fmaxf(m_i[i], mx);
      float scl = __expf(m_i[i] - mnew);
      float ps = 0.f;
#pragma unroll
      for (int nf = 0; nf < 4; ++nf) {
        p[nf][i] = __expf(sacc[nf][i] - mnew);
        ps += p[nf][i];
      }
#pragma unroll
      for (int off = 1; off < 16; off <<= 1) ps += __shfl_xor(ps, off, 64);
      l_i[i] = l_i[i] * scl + ps;
      m_i[i] = mnew;
#pragma unroll
      for (int f = 0; f < 4; ++f) of[f][i] *= scl;
    }

    // write P (bf16) to wave-private swizzled LDS
    u16* Pw = (u16*)Pl[w];
#pragma unroll
    for (int nf = 0; nf < 4; ++nf)
#pragma unroll
      for (int i = 0; i < 4; ++i) {
        int row = lg * 4 + i, col = l16 + nf * 16;
        *(u16*)((char*)Pw + row * 128 + ((col * 2) ^ ((row & 7) << 4))) = f2bf(p[nf][i]);
      }

    // PV : of += P @ V
#pragma unroll
    for (int ks = 0; ks < 2; ++ks) {
      int prow = l16;
      bf16x8 pf = *(const bf16x8*)((const char*)Pw + prow * 128 +
                                   ((lg * 16 + ks * 64) ^ ((prow & 7) << 4)));
#pragma unroll
      for (int nf = 0; nf < 4; ++nf) {
        int vrow = l16 + nf * 16;
        bf16x8 vf = *(const bf16x8*)((const char*)Vt + vrow * 128 +
                                     ((lg * 16 + ks * 64) ^ ((vrow & 7) << 4)));
        of[nf] = __builtin_amdgcn_mfma_f32_16x16x32_bf16(pf, vf, of[nf], 0, 0, 0);
      }
    }
    __syncthreads();
  }

  // epilogue: normalize and write Ob [B*S][768]
#pragma unroll
  for (int i = 0; i < 4; ++i) {
    float inv = 1.0f / l_i[i];
    int sq = sq0 + lg * 4 + i;
#pragma unroll
    for (int f = 0; f < 4; ++f) {
      int d = h * 64 + l16 + f * 16;
      Ob[(size_t)(b * S + sq) * D + d] = f2bf(of[f][i] * inv);
    }
  }
}

extern "C" void kernel_launch(void* const* d_in, const int* in_sizes, int n_in,
                              void* d_out, int out_size, void* d_ws, size_t ws_size,
                              hipStream_t stream) {
  const float* x      = (const float*)d_in[0];
  const float* qkv_w  = (const float*)d_in[1];
  const float* qkv_b  = (const float*)d_in[2];
  const float* proj_w = (const float*)d_in[3];
  const float* proj_b = (const float*)d_in[4];
  float* out = (float*)d_out;

  u16* ws  = (u16*)d_ws;
  u16* xb  = ws;                       // 8192*768
  u16* wt  = xb + 8192 * 768;          // 2304*768
  u16* pwt = wt + 2304 * 768;          // 768*768
  u16* Qb  = pwt + 768 * 768;          // 24*4096*64
  u16* Kb  = Qb + 24 * 4096 * 64;
  u16* Vb  = Kb + 24 * 4096 * 64;
  u16* Ob  = Vb + 24 * 4096 * 64;      // 8192*768

  k_f32_to_bf16<<<6144, 256, 0, stream>>>(x, xb, 8192 * 768 / 4);
  k_transpose_bf16<<<dim3(72, 24), dim3(32, 8), 0, stream>>>(qkv_w, wt, 768, 2304);
  k_transpose_bf16<<<dim3(24, 24), dim3(32, 8), 0, stream>>>(proj_w, pwt, 768, 768);
  k_gemm_qkv<<<dim3(18, 64), 256, 0, stream>>>(xb, wt, qkv_b, Qb, Kb, Vb);
  k_attn<<<1536, 256, 0, stream>>>(Qb, Kb, Vb, Ob);
  k_gemm_proj<<<dim3(6, 64), 256, 0, stream>>>(Ob, pwt, proj_b, out);
}

// Round 3
// 352.719 us; speedup vs baseline: 1.2194x; 1.2194x over previous
//
#include <hip/hip_runtime.h>

typedef unsigned short u16;
typedef __attribute__((ext_vector_type(8))) short bf16x8;
typedef __attribute__((ext_vector_type(4))) float f32x4;

__device__ __forceinline__ u16 f2bf(float f) {
  union { float f; unsigned u; } v; v.f = f;
  unsigned r = v.u + 0x7fffu + ((v.u >> 16) & 1u);
  return (u16)(r >> 16);
}
__device__ __forceinline__ float bf2f(u16 h) {
  union { unsigned u; float f; } v; v.u = ((unsigned)h) << 16;
  return v.f;
}

__device__ __forceinline__ bf16x8 ld_frag(const char* p) {
  union { uint4 u; bf16x8 v; } t;
  t.u = *(const uint4*)p;
  return t.v;
}

// ---------------- fp32 -> bf16 convert (vectorized) ----------------
__global__ __launch_bounds__(256) void k_f32_to_bf16(const float* __restrict__ in,
                                                     u16* __restrict__ out, int n4) {
  int i = blockIdx.x * 256 + threadIdx.x;
  if (i < n4) {
    float4 v = ((const float4*)in)[i];
    ushort4 o; o.x = f2bf(v.x); o.y = f2bf(v.y); o.z = f2bf(v.z); o.w = f2bf(v.w);
    ((ushort4*)out)[i] = o;
  }
}

// ---------------- fp32 [R][C] -> bf16 [C][R] transpose ----------------
__global__ __launch_bounds__(256) void k_transpose_bf16(const float* __restrict__ in,
                                                        u16* __restrict__ out,
                                                        int R, int C) {
  __shared__ float tile[32][33];
  int bx = blockIdx.x * 32;
  int by = blockIdx.y * 32;
  int tx = threadIdx.x, ty = threadIdx.y;  // (32, 8)
#pragma unroll
  for (int j = 0; j < 32; j += 8)
    tile[ty + j][tx] = in[(size_t)(by + ty + j) * C + bx + tx];
  __syncthreads();
#pragma unroll
  for (int j = 0; j < 32; j += 8)
    out[(size_t)(bx + ty + j) * R + by + tx] = f2bf(tile[tx][ty + j]);
}

#define GAS(p) ((const __attribute__((address_space(1))) void*)(p))
#define LAS(p) ((__attribute__((address_space(3))) void*)(p))

// ---------------- QKV GEMM: [8192,768] x [768,2304] + bias, scatter Q/K row-major, V transposed ----------------
__global__ __launch_bounds__(256) void k_gemm_qkv(
    const u16* __restrict__ A,   // xb [8192][768]
    const u16* __restrict__ Bt,  // wt  [2304][768]
    const float* __restrict__ bias,
    u16* __restrict__ Qb, u16* __restrict__ Kb, u16* __restrict__ Vb) {
  const int K = 768;
  __shared__ u16 Al[128 * 64];
  __shared__ u16 Bl[128 * 64];
  int tn0 = blockIdx.x * 128, tm0 = blockIdx.y * 128;
  int tid = threadIdx.x, w = tid >> 6, lane = tid & 63;
  int l16 = lane & 15, lg = lane >> 4;
  int wm = (w >> 1) * 64, wn = (w & 1) * 64;
  f32x4 acc[4][4];
#pragma unroll
  for (int fm = 0; fm < 4; ++fm)
#pragma unroll
    for (int fn = 0; fn < 4; ++fn) acc[fm][fn] = (f32x4){0.f, 0.f, 0.f, 0.f};
  int srow = w * 32 + (lane >> 3);
  int scol = (lane & 7) * 8;
  for (int k0 = 0; k0 < K; k0 += 64) {
#pragma unroll
    for (int i = 0; i < 4; ++i) {
      __builtin_amdgcn_global_load_lds(GAS(A + (size_t)(tm0 + srow + i * 8) * K + k0 + scol),
                                       LAS((char*)Al + w * 4096 + i * 1024 + lane * 16), 16, 0, 0);
      __builtin_amdgcn_global_load_lds(GAS(Bt + (size_t)(tn0 + srow + i * 8) * K + k0 + scol),
                                       LAS((char*)Bl + w * 4096 + i * 1024 + lane * 16), 16, 0, 0);
    }
    __syncthreads();
#pragma unroll
    for (int ks = 0; ks < 2; ++ks) {
      bf16x8 af[4], bv[4];
#pragma unroll
      for (int f = 0; f < 4; ++f)
        af[f] = *(const bf16x8*)&Al[(wm + f * 16 + l16) * 64 + lg * 8 + ks * 32];
#pragma unroll
      for (int f = 0; f < 4; ++f)
        bv[f] = *(const bf16x8*)&Bl[(wn + f * 16 + l16) * 64 + lg * 8 + ks * 32];
#pragma unroll
      for (int fm = 0; fm < 4; ++fm)
#pragma unroll
        for (int fn = 0; fn < 4; ++fn)
          acc[fm][fn] = __builtin_amdgcn_mfma_f32_16x16x32_bf16(af[fm], bv[fn], acc[fm][fn], 0, 0, 0);
    }
    __syncthreads();
  }
  int part = tn0 / 768;  // block-uniform (768 = 6*128)
  u16* dst = part == 0 ? Qb : (part == 1 ? Kb : Vb);
#pragma unroll
  for (int fn = 0; fn < 4; ++fn) {
    int nn = tn0 + wn + fn * 16 + l16;
    float bvs = bias[nn];
    int np = nn - part * 768;
    int hh = np >> 6, hd = np & 63;
#pragma unroll
    for (int fm = 0; fm < 4; ++fm) {
#pragma unroll
      for (int r = 0; r < 4; ++r) {
        int m = tm0 + wm + fm * 16 + lg * 4 + r;
        int bb = m >> 12, s = m & 4095;
        size_t idx = (part == 2)
            ? (((size_t)(bb * 12 + hh)) * 64 + hd) * 4096 + s   // V^T [bh][hd][S]
            : (((size_t)(bb * 12 + hh)) * 4096 + s) * 64 + hd;  // Q/K [bh][S][64]
        dst[idx] = f2bf(acc[fm][fn][r] + bvs);
      }
    }
  }
}

// ---------------- proj GEMM: [8192,768] x [768,768] + bias -> fp32 out ----------------
__global__ __launch_bounds__(256) void k_gemm_proj(
    const u16* __restrict__ A,   // Ob [8192][768]
    const u16* __restrict__ Bt,  // pwt [768][768]
    const float* __restrict__ bias, float* __restrict__ out) {
  const int K = 768;
  __shared__ u16 Al[128 * 64];
  __shared__ u16 Bl[128 * 64];
  int tn0 = blockIdx.x * 128, tm0 = blockIdx.y * 128;
  int tid = threadIdx.x, w = tid >> 6, lane = tid & 63;
  int l16 = lane & 15, lg = lane >> 4;
  int wm = (w >> 1) * 64, wn = (w & 1) * 64;
  f32x4 acc[4][4];
#pragma unroll
  for (int fm = 0; fm < 4; ++fm)
#pragma unroll
    for (int fn = 0; fn < 4; ++fn) acc[fm][fn] = (f32x4){0.f, 0.f, 0.f, 0.f};
  int srow = w * 32 + (lane >> 3);
  int scol = (lane & 7) * 8;
  for (int k0 = 0; k0 < K; k0 += 64) {
#pragma unroll
    for (int i = 0; i < 4; ++i) {
      __builtin_amdgcn_global_load_lds(GAS(A + (size_t)(tm0 + srow + i * 8) * K + k0 + scol),
                                       LAS((char*)Al + w * 4096 + i * 1024 + lane * 16), 16, 0, 0);
      __builtin_amdgcn_global_load_lds(GAS(Bt + (size_t)(tn0 + srow + i * 8) * K + k0 + scol),
                                       LAS((char*)Bl + w * 4096 + i * 1024 + lane * 16), 16, 0, 0);
    }
    __syncthreads();
#pragma unroll
    for (int ks = 0; ks < 2; ++ks) {
      bf16x8 af[4], bv[4];
#pragma unroll
      for (int f = 0; f < 4; ++f)
        af[f] = *(const bf16x8*)&Al[(wm + f * 16 + l16) * 64 + lg * 8 + ks * 32];
#pragma unroll
      for (int f = 0; f < 4; ++f)
        bv[f] = *(const bf16x8*)&Bl[(wn + f * 16 + l16) * 64 + lg * 8 + ks * 32];
#pragma unroll
      for (int fm = 0; fm < 4; ++fm)
#pragma unroll
        for (int fn = 0; fn < 4; ++fn)
          acc[fm][fn] = __builtin_amdgcn_mfma_f32_16x16x32_bf16(af[fm], bv[fn], acc[fm][fn], 0, 0, 0);
    }
    __syncthreads();
  }
#pragma unroll
  for (int fn = 0; fn < 4; ++fn) {
    int nn = tn0 + wn + fn * 16 + l16;
    float bvs = bias[nn];
#pragma unroll
    for (int fm = 0; fm < 4; ++fm) {
#pragma unroll
      for (int r = 0; r < 4; ++r) {
        int m = tm0 + wm + fm * 16 + lg * 4 + r;
        out[(size_t)m * 768 + nn] = acc[fm][fn][r] + bvs;
      }
    }
  }
}

// ---------------- flash attention ----------------
// 768 blocks = 24 bh x 32 q-pairs; each block: 128 q rows (2 tiles of 64), 4 waves x 16 q-rows/tile.
// Swapped QK^T (mfma(K,Q)): lane l16 owns q-row, but the 64 sk scores are spread across
// the 4 lanes {l16, l16+16, l16+32, l16+48} -> softmax reduce = 15 in-lane fmax + shfl_xor(16,32).
// Swapped PV (mfma(V^T,P)). K and V^T staged via global_load_lds (pre-swizzled source), dbuf.
__global__ __launch_bounds__(256, 4) void k_attn(const u16* __restrict__ Qb,
                                                 const u16* __restrict__ Kb,
                                                 const u16* __restrict__ Vtg,
                                                 u16* __restrict__ Ob) {
  const int S = 4096, HD = 64, NH = 12, D = 768;
  __shared__ u16 Kl[2][64 * 64];     // [sk][hd], linear, swizzle applied on read (source pre-swizzled)
  __shared__ u16 Vl[2][64 * 64];     // [hd][sk], same
  __shared__ unsigned Pl[4][512];    // per-wave P[q=16][sk=64] bf16, swizzled

  int bid0 = blockIdx.x;
  int bid = (bid0 & 7) * 96 + (bid0 >> 3);   // XCD-bijective swizzle (768 % 8 == 0)
  int qp = bid & 31;    // q-pair index
  int bh = bid >> 5;    // 0..23
  int b = bh / NH, h = bh % NH;
  const u16* Qh = Qb + (size_t)bh * S * HD;
  const char* Khc = (const char*)(Kb + (size_t)bh * S * HD);
  const char* Vhc = (const char*)(Vtg + (size_t)bh * HD * S);

  int tid = threadIdx.x, w = tid >> 6, lane = tid & 63;
  int l16 = lane & 15, lg = lane >> 4;
  int swl = (l16 & 7) << 4;

  // staging: wave w stages rows w*16..w*16+15 of each 64x64 tile; chunk pre-swizzled in source
  int r8 = lane >> 3;
  int chs = (lane & 7) ^ r8;
  const char* kSrc = Khc + (size_t)(w * 16 + r8) * 128 + chs * 16;   // + kv*8192 + qq*1024
  const char* vSrc = Vhc + (size_t)(w * 16 + r8) * 8192 + chs * 16;  // + qq*65536 + kv*128
  char* kDst0 = (char*)&Kl[0][0] + w * 2048 + lane * 16;
  char* vDst0 = (char*)&Vl[0][0] + w * 2048 + lane * 16;

  auto STAGE = [&](int bufi, int kv) {
#pragma unroll
    for (int qq = 0; qq < 2; ++qq) {
      __builtin_amdgcn_global_load_lds(GAS(kSrc + (size_t)kv * 8192 + qq * 1024),
                                       LAS(kDst0 + bufi * 8192 + qq * 1024), 16, 0, 0);
      __builtin_amdgcn_global_load_lds(GAS(vSrc + (size_t)qq * 65536 + (size_t)kv * 128),
                                       LAS(vDst0 + bufi * 8192 + qq * 1024), 16, 0, 0);
    }
  };

  // Q fragments for both q-tiles, pre-scaled by 1/8 (exact in bf16)
  int sq0A = qp * 128 + w * 16;
  int sq0B = sq0A + 64;
  bf16x8 qfA[2], qfB[2];
#pragma unroll
  for (int ks = 0; ks < 2; ++ks) {
    bf16x8 qa = *(const bf16x8*)&Qh[(size_t)(sq0A + l16) * HD + lg * 8 + ks * 32];
    bf16x8 qb2 = *(const bf16x8*)&Qh[(size_t)(sq0B + l16) * HD + lg * 8 + ks * 32];
#pragma unroll
    for (int j = 0; j < 8; ++j) {
      qa[j] = (short)f2bf(bf2f((u16)qa[j]) * 0.125f);
      qb2[j] = (short)f2bf(bf2f((u16)qb2[j]) * 0.125f);
    }
    qfA[ks] = qa; qfB[ks] = qb2;
  }

  f32x4 ofA[4], ofB[4];
  float mA = -1e30f, lA = 0.f, mB = -1e30f, lB = 0.f;
#pragma unroll
  for (int f = 0; f < 4; ++f) { ofA[f] = (f32x4){0.f,0.f,0.f,0.f}; ofB[f] = (f32x4){0.f,0.f,0.f,0.f}; }

  char* Pb = (char*)&Pl[w][0];

  STAGE(0, 0);
  __syncthreads();
  int cur = 0;

  for (int kv = 0; kv < S / 64; ++kv) {
    if (kv < S / 64 - 1) STAGE(cur ^ 1, kv + 1);
    const char* curK = (const char*)&Kl[0][0] + cur * 8192;
    const char* curV = (const char*)&Vl[0][0] + cur * 8192;

    auto qtile = [&](bf16x8 (&qf)[2], f32x4 (&of)[4], float& m_i, float& l_i) {
      // QK^T swapped: sacc[nf][i] = S^T[sk = nf*16 + lg*4 + i][q = l16]
      f32x4 sacc[4];
#pragma unroll
      for (int f = 0; f < 4; ++f) sacc[f] = (f32x4){0.f, 0.f, 0.f, 0.f};
#pragma unroll
      for (int ks = 0; ks < 2; ++ks) {
#pragma unroll
        for (int nf = 0; nf < 4; ++nf) {
          bf16x8 kf = ld_frag(curK + (nf * 16 + l16) * 128 + ((lg * 16 + ks * 64) ^ swl));
          sacc[nf] = __builtin_amdgcn_mfma_f32_16x16x32_bf16(kf, qf[ks], sacc[nf], 0, 0, 0);
        }
      }
      // softmax for q-row l16: 16 in-lane values + cross-lane reduce over lg group
      float mx = sacc[0][0];
#pragma unroll
      for (int nf = 0; nf < 4; ++nf)
#pragma unroll
        for (int i = 0; i < 4; ++i) mx = fmaxf(mx, sacc[nf][i]);
      mx = fmaxf(mx, __shfl_xor(mx, 16, 64));
      mx = fmaxf(mx, __shfl_xor(mx, 32, 64));
      if (mx > m_i + 8.f) {   // defer-max: skip rescale when growth small
        float scl = __expf(m_i - mx);
        m_i = mx; l_i *= scl;
#pragma unroll
        for (int nf = 0; nf < 4; ++nf)
#pragma unroll
          for (int i = 0; i < 4; ++i) of[nf][i] *= scl;
      }
      float ps = 0.f;
#pragma unroll
      for (int nf = 0; nf < 4; ++nf)
#pragma unroll
        for (int i = 0; i < 4; ++i) {
          float pp = __expf(sacc[nf][i] - m_i);
          sacc[nf][i] = pp;   // reuse regs: sacc now holds P
          ps += pp;
        }
      ps += __shfl_xor(ps, 16, 64);
      ps += __shfl_xor(ps, 32, 64);
      l_i += ps;
      // pack P -> bf16 pairs, write wave-private LDS P[q=l16][sk]
#pragma unroll
      for (int nf = 0; nf < 4; ++nf)
#pragma unroll
        for (int hh = 0; hh < 2; ++hh) {
          unsigned pk;
          asm("v_cvt_pk_bf16_f32 %0, %1, %2" : "=v"(pk)
              : "v"(sacc[nf][2 * hh]), "v"(sacc[nf][2 * hh + 1]));
          int colb = (nf * 16 + lg * 4 + 2 * hh) * 2;
          *(unsigned*)(Pb + l16 * 128 + (colb ^ swl)) = pk;
        }
      // PV swapped: of[nf][i] = O^T[hd = nf*16 + lg*4 + i][q = l16]
#pragma unroll
      for (int ks = 0; ks < 2; ++ks) {
        bf16x8 pf = ld_frag(Pb + l16 * 128 + ((ks * 64 + lg * 16) ^ swl));
#pragma unroll
        for (int nf = 0; nf < 4; ++nf) {
          bf16x8 vf = ld_frag(curV + (nf * 16 + l16) * 128 + ((lg * 16 + ks * 64) ^ swl));
          of[nf] = __builtin_amdgcn_mfma_f32_16x16x32_bf16(vf, pf, of[nf], 0, 0, 0);
        }
      }
    };

    qtile(qfA, ofA, mA, lA);
    qtile(qfB, ofB, mB, lB);

    if (kv < S / 64 - 1) { __syncthreads(); cur ^= 1; }
  }

  // epilogue: lane owns q = sq0 + l16, 16 hd values
  auto wout = [&](f32x4 (&of)[4], float l_i, int sq0) {
    float inv = 1.f / l_i;
    int q = sq0 + l16;
    u16* orow = Ob + (size_t)(b * S + q) * D + h * 64;
#pragma unroll
    for (int nf = 0; nf < 4; ++nf) {
      ushort4 o;
      o.x = f2bf(of[nf][0] * inv); o.y = f2bf(of[nf][1] * inv);
      o.z = f2bf(of[nf][2] * inv); o.w = f2bf(of[nf][3] * inv);
      *(ushort4*)(orow + nf * 16 + lg * 4) = o;
    }
  };
  wout(ofA, lA, sq0A);
  wout(ofB, lB, sq0B);
}

extern "C" void kernel_launch(void* const* d_in, const int* in_sizes, int n_in,
                              void* d_out, int out_size, void* d_ws, size_t ws_size,
                              hipStream_t stream) {
  const float* x      = (const float*)d_in[0];
  const float* qkv_w  = (const float*)d_in[1];
  const float* qkv_b  = (const float*)d_in[2];
  const float* proj_w = (const float*)d_in[3];
  const float* proj_b = (const float*)d_in[4];
  float* out = (float*)d_out;

  u16* ws  = (u16*)d_ws;
  u16* xb  = ws;                       // 8192*768
  u16* wt  = xb + 8192 * 768;          // 2304*768
  u16* pwt = wt + 2304 * 768;          // 768*768
  u16* Qb  = pwt + 768 * 768;          // 24*4096*64  [bh][S][64]
  u16* Kb  = Qb + 24 * 4096 * 64;      // [bh][S][64]
  u16* Vt  = Kb + 24 * 4096 * 64;      // [bh][64][S]  (V transposed)
  u16* Ob  = Vt + 24 * 4096 * 64;      // 8192*768

  k_f32_to_bf16<<<6144, 256, 0, stream>>>(x, xb, 8192 * 768 / 4);
  k_transpose_bf16<<<dim3(72, 24), dim3(32, 8), 0, stream>>>(qkv_w, wt, 768, 2304);
  k_transpose_bf16<<<dim3(24, 24), dim3(32, 8), 0, stream>>>(proj_w, pwt, 768, 768);
  k_gemm_qkv<<<dim3(18, 64), 256, 0, stream>>>(xb, wt, qkv_b, Qb, Kb, Vt);
  k_attn<<<768, 256, 0, stream>>>(Qb, Kb, Vt, Ob);
  k_gemm_proj<<<dim3(6, 64), 256, 0, stream>>>(Ob, pwt, proj_b, out);
}

// Round 4
// 288.853 us; speedup vs baseline: 1.4890x; 1.2211x over previous
//
#include <hip/hip_runtime.h>

typedef unsigned short u16;
typedef __attribute__((ext_vector_type(8))) short bf16x8;
typedef __attribute__((ext_vector_type(4))) float f32x4;
typedef __attribute__((ext_vector_type(16))) float f32x16;

__device__ __forceinline__ u16 f2bf(float f) {
  union { float f; unsigned u; } v; v.f = f;
  unsigned r = v.u + 0x7fffu + ((v.u >> 16) & 1u);
  return (u16)(r >> 16);
}
__device__ __forceinline__ float bf2f(u16 h) {
  union { unsigned u; float f; } v; v.u = ((unsigned)h) << 16;
  return v.f;
}

__device__ __forceinline__ bf16x8 ld_frag(const char* p) {
  union { uint4 u; bf16x8 v; } t;
  t.u = *(const uint4*)p;
  return t.v;
}

// ---------------- fp32 -> bf16 convert (vectorized) ----------------
__global__ __launch_bounds__(256) void k_f32_to_bf16(const float* __restrict__ in,
                                                     u16* __restrict__ out, int n4) {
  int i = blockIdx.x * 256 + threadIdx.x;
  if (i < n4) {
    float4 v = ((const float4*)in)[i];
    ushort4 o; o.x = f2bf(v.x); o.y = f2bf(v.y); o.z = f2bf(v.z); o.w = f2bf(v.w);
    ((ushort4*)out)[i] = o;
  }
}

// ---------------- fp32 [R][C] -> bf16 [C][R] transpose ----------------
__global__ __launch_bounds__(256) void k_transpose_bf16(const float* __restrict__ in,
                                                        u16* __restrict__ out,
                                                        int R, int C) {
  __shared__ float tile[32][33];
  int bx = blockIdx.x * 32;
  int by = blockIdx.y * 32;
  int tx = threadIdx.x, ty = threadIdx.y;  // (32, 8)
#pragma unroll
  for (int j = 0; j < 32; j += 8)
    tile[ty + j][tx] = in[(size_t)(by + ty + j) * C + bx + tx];
  __syncthreads();
#pragma unroll
  for (int j = 0; j < 32; j += 8)
    out[(size_t)(bx + ty + j) * R + by + tx] = f2bf(tile[tx][ty + j]);
}

#define GAS(p) ((const __attribute__((address_space(1))) void*)(p))
#define LAS(p) ((__attribute__((address_space(3))) void*)(p))

// ---------------- QKV GEMM: [8192,768] x [768,2304] + bias, scatter Q/K row-major, V transposed+col-permuted ----------------
__global__ __launch_bounds__(256) void k_gemm_qkv(
    const u16* __restrict__ A,   // xb [8192][768]
    const u16* __restrict__ Bt,  // wt  [2304][768]
    const float* __restrict__ bias,
    u16* __restrict__ Qb, u16* __restrict__ Kb, u16* __restrict__ Vb) {
  const int K = 768;
  __shared__ u16 Al[128 * 64];
  __shared__ u16 Bl[128 * 64];
  int tn0 = blockIdx.x * 128, tm0 = blockIdx.y * 128;
  int tid = threadIdx.x, w = tid >> 6, lane = tid & 63;
  int l16 = lane & 15, lg = lane >> 4;
  int wm = (w >> 1) * 64, wn = (w & 1) * 64;
  f32x4 acc[4][4];
#pragma unroll
  for (int fm = 0; fm < 4; ++fm)
#pragma unroll
    for (int fn = 0; fn < 4; ++fn) acc[fm][fn] = (f32x4){0.f, 0.f, 0.f, 0.f};
  int srow = w * 32 + (lane >> 3);
  int scol = (lane & 7) * 8;
  for (int k0 = 0; k0 < K; k0 += 64) {
#pragma unroll
    for (int i = 0; i < 4; ++i) {
      __builtin_amdgcn_global_load_lds(GAS(A + (size_t)(tm0 + srow + i * 8) * K + k0 + scol),
                                       LAS((char*)Al + w * 4096 + i * 1024 + lane * 16), 16, 0, 0);
      __builtin_amdgcn_global_load_lds(GAS(Bt + (size_t)(tn0 + srow + i * 8) * K + k0 + scol),
                                       LAS((char*)Bl + w * 4096 + i * 1024 + lane * 16), 16, 0, 0);
    }
    __syncthreads();
#pragma unroll
    for (int ks = 0; ks < 2; ++ks) {
      bf16x8 af[4], bv[4];
#pragma unroll
      for (int f = 0; f < 4; ++f)
        af[f] = *(const bf16x8*)&Al[(wm + f * 16 + l16) * 64 + lg * 8 + ks * 32];
#pragma unroll
      for (int f = 0; f < 4; ++f)
        bv[f] = *(const bf16x8*)&Bl[(wn + f * 16 + l16) * 64 + lg * 8 + ks * 32];
#pragma unroll
      for (int fm = 0; fm < 4; ++fm)
#pragma unroll
        for (int fn = 0; fn < 4; ++fn)
          acc[fm][fn] = __builtin_amdgcn_mfma_f32_16x16x32_bf16(af[fm], bv[fn], acc[fm][fn], 0, 0, 0);
    }
    __syncthreads();
  }
  int part = tn0 / 768;  // block-uniform (768 = 6*128)
  u16* dst = part == 0 ? Qb : (part == 1 ? Kb : Vb);
#pragma unroll
  for (int fn = 0; fn < 4; ++fn) {
    int nn = tn0 + wn + fn * 16 + l16;
    float bvs = bias[nn];
    int np = nn - part * 768;
    int hh = np >> 6, hd = np & 63;
#pragma unroll
    for (int fm = 0; fm < 4; ++fm) {
#pragma unroll
      for (int r = 0; r < 4; ++r) {
        int m = tm0 + wm + fm * 16 + lg * 4 + r;
        int bb = m >> 12, s = m & 4095;
        size_t idx;
        if (part == 2) {
          // V^T [bh][hd][S], sk columns permuted: swap bits 2<->3 of s
          int sp = (s & ~12) | ((s & 8) >> 1) | ((s & 4) << 1);
          idx = (((size_t)(bb * 12 + hh)) * 64 + hd) * 4096 + sp;
        } else {
          idx = (((size_t)(bb * 12 + hh)) * 4096 + s) * 64 + hd;  // Q/K [bh][S][64]
        }
        dst[idx] = f2bf(acc[fm][fn][r] + bvs);
      }
    }
  }
}

// ---------------- proj GEMM: [8192,768] x [768,768] + bias -> fp32 out ----------------
__global__ __launch_bounds__(256) void k_gemm_proj(
    const u16* __restrict__ A,   // Ob [8192][768]
    const u16* __restrict__ Bt,  // pwt [768][768]
    const float* __restrict__ bias, float* __restrict__ out) {
  const int K = 768;
  __shared__ u16 Al[128 * 64];
  __shared__ u16 Bl[128 * 64];
  int tn0 = blockIdx.x * 128, tm0 = blockIdx.y * 128;
  int tid = threadIdx.x, w = tid >> 6, lane = tid & 63;
  int l16 = lane & 15, lg = lane >> 4;
  int wm = (w >> 1) * 64, wn = (w & 1) * 64;
  f32x4 acc[4][4];
#pragma unroll
  for (int fm = 0; fm < 4; ++fm)
#pragma unroll
    for (int fn = 0; fn < 4; ++fn) acc[fm][fn] = (f32x4){0.f, 0.f, 0.f, 0.f};
  int srow = w * 32 + (lane >> 3);
  int scol = (lane & 7) * 8;
  for (int k0 = 0; k0 < K; k0 += 64) {
#pragma unroll
    for (int i = 0; i < 4; ++i) {
      __builtin_amdgcn_global_load_lds(GAS(A + (size_t)(tm0 + srow + i * 8) * K + k0 + scol),
                                       LAS((char*)Al + w * 4096 + i * 1024 + lane * 16), 16, 0, 0);
      __builtin_amdgcn_global_load_lds(GAS(Bt + (size_t)(tn0 + srow + i * 8) * K + k0 + scol),
                                       LAS((char*)Bl + w * 4096 + i * 1024 + lane * 16), 16, 0, 0);
    }
    __syncthreads();
#pragma unroll
    for (int ks = 0; ks < 2; ++ks) {
      bf16x8 af[4], bv[4];
#pragma unroll
      for (int f = 0; f < 4; ++f)
        af[f] = *(const bf16x8*)&Al[(wm + f * 16 + l16) * 64 + lg * 8 + ks * 32];
#pragma unroll
      for (int f = 0; f < 4; ++f)
        bv[f] = *(const bf16x8*)&Bl[(wn + f * 16 + l16) * 64 + lg * 8 + ks * 32];
#pragma unroll
      for (int fm = 0; fm < 4; ++fm)
#pragma unroll
        for (int fn = 0; fn < 4; ++fn)
          acc[fm][fn] = __builtin_amdgcn_mfma_f32_16x16x32_bf16(af[fm], bv[fn], acc[fm][fn], 0, 0, 0);
    }
    __syncthreads();
  }
#pragma unroll
  for (int fn = 0; fn < 4; ++fn) {
    int nn = tn0 + wn + fn * 16 + l16;
    float bvs = bias[nn];
#pragma unroll
    for (int fm = 0; fm < 4; ++fm) {
#pragma unroll
      for (int r = 0; r < 4; ++r) {
        int m = tm0 + wm + fm * 16 + lg * 4 + r;
        out[(size_t)m * 768 + nn] = acc[fm][fn][r] + bvs;
      }
    }
  }
}

// ---------------- flash attention, 32x32 MFMA, in-register P ----------------
// 768 blocks = 24 bh x 32 q-groups of 128; 4 waves x 32 q-rows.
// Swapped QK^T: mfma_32x32x16(K, Q) -> lane (q=lane&31, hi=lane>>5) owns 32 of 64 sk scores.
// Softmax: 1 shfl_xor(32) for max; l-sum combined only at epilogue.
// PV: V^T staged with sk columns bit2<->3 permuted (done in QKV epilogue), so the P
// B-fragment is the accumulator in natural order -> 16 cvt_pk, no shuffles, no P LDS.
__global__ __launch_bounds__(256, 3) void k_attn(const u16* __restrict__ Qb,
                                                 const u16* __restrict__ Kb,
                                                 const u16* __restrict__ Vtg,
                                                 u16* __restrict__ Ob) {
  const int S = 4096, NH = 12, D = 768;
  __shared__ u16 Kl[2][64 * 64];     // [sk][hd] 128B rows, chunk-XOR swizzled via pre-swizzled source
  __shared__ u16 Vl[2][64 * 64];     // [hd][sk(perm)] same

  int bid0 = blockIdx.x;
  int bid = (bid0 & 7) * 96 + (bid0 >> 3);   // XCD-bijective swizzle (768 % 8 == 0)
  int qp = bid & 31;
  int bh = bid >> 5;
  int b = bh / NH, h = bh % NH;
  const u16* Qh = Qb + (size_t)bh * S * 64;
  const char* Khc = (const char*)(Kb + (size_t)bh * S * 64);
  const char* Vhc = (const char*)(Vtg + (size_t)bh * 64 * S);

  int tid = threadIdx.x, w = tid >> 6, lane = tid & 63;
  int q31 = lane & 31, hi = lane >> 5;
  int swb = (q31 & 7) << 4;          // read-side XOR: row&7 (rows read are base + q31, base%32==0)
  int coff = (hi << 4);              // hi*16 byte offset within 32B k-chunk pair

  // staging (unchanged): wave w stages rows w*16..w*16+15 of each 64x64 tile, pre-swizzled source chunk
  int r8 = lane >> 3;
  int chs = (lane & 7) ^ r8;
  const char* kSrc = Khc + (size_t)(w * 16 + r8) * 128 + chs * 16;
  const char* vSrc = Vhc + (size_t)(w * 16 + r8) * 8192 + chs * 16;
  char* kDst0 = (char*)&Kl[0][0] + w * 2048 + lane * 16;
  char* vDst0 = (char*)&Vl[0][0] + w * 2048 + lane * 16;

  auto STAGE = [&](int bufi, int kv) {
#pragma unroll
    for (int qq = 0; qq < 2; ++qq) {
      __builtin_amdgcn_global_load_lds(GAS(kSrc + (size_t)kv * 8192 + qq * 1024),
                                       LAS(kDst0 + bufi * 8192 + qq * 1024), 16, 0, 0);
      __builtin_amdgcn_global_load_lds(GAS(vSrc + (size_t)qq * 65536 + (size_t)kv * 128),
                                       LAS(vDst0 + bufi * 8192 + qq * 1024), 16, 0, 0);
    }
  };

  // Q fragments (B-operand): lane supplies Q[q31][k = ks*16 + hi*8 + j]; no pre-scale (folded into exp2)
  int qbase = qp * 128 + w * 32;
  const u16* qrow = Qh + (size_t)(qbase + q31) * 64;
  bf16x8 qf[4];
#pragma unroll
  for (int ks = 0; ks < 4; ++ks)
    qf[ks] = *(const bf16x8*)(qrow + ks * 16 + hi * 8);

  f32x16 of0, of1;
#pragma unroll
  for (int i = 0; i < 16; ++i) { of0[i] = 0.f; of1[i] = 0.f; }
  float m2 = -1e30f, l_own = 0.f;
  const float CSC = 0.18033688011112042f;  // log2(e) / 8

  STAGE(0, 0);
  __syncthreads();
  int cur = 0;

  for (int kv = 0; kv < S / 64; ++kv) {
    if (kv < S / 64 - 1) STAGE(cur ^ 1, kv + 1);
    const char* curK = (const char*)&Kl[0][0] + cur * 8192;
    const char* curV = (const char*)&Vl[0][0] + cur * 8192;

    // ---- QK^T: s0 = S^T[sk 0..31][q], s1 = S^T[sk 32..63][q]
    f32x16 s0, s1;
#pragma unroll
    for (int i = 0; i < 16; ++i) { s0[i] = 0.f; s1[i] = 0.f; }
#pragma unroll
    for (int ks = 0; ks < 4; ++ks) {
      bf16x8 kf = ld_frag(curK + q31 * 128 + ((ks * 32 + coff) ^ swb));
      s0 = __builtin_amdgcn_mfma_f32_32x32x16_bf16(kf, qf[ks], s0, 0, 0, 0);
    }
#pragma unroll
    for (int ks = 0; ks < 4; ++ks) {
      bf16x8 kf = ld_frag(curK + (32 + q31) * 128 + ((ks * 32 + coff) ^ swb));
      s1 = __builtin_amdgcn_mfma_f32_32x32x16_bf16(kf, qf[ks], s1, 0, 0, 0);
    }

    // ---- softmax for q-row q31 (raw-score max tree, then exp2 domain)
    float t[16];
#pragma unroll
    for (int i = 0; i < 16; ++i) t[i] = fmaxf(s0[i], s1[i]);
#pragma unroll
    for (int st = 8; st >= 1; st >>= 1)
#pragma unroll
      for (int i = 0; i < 8; ++i)
        if (i < st) t[i] = fmaxf(t[i], t[i + st]);
    float mx = fmaxf(t[0], __shfl_xor(t[0], 32, 64));
    float mx2 = mx * CSC;
    if (mx2 > m2 + 8.f) {            // defer-max (THR=8 in log2 domain)
      float scl = exp2f(m2 - mx2);
      m2 = mx2; l_own *= scl;
#pragma unroll
      for (int i = 0; i < 16; ++i) { of0[i] *= scl; of1[i] *= scl; }
    }
    float nm2 = -m2;
#pragma unroll
    for (int i = 0; i < 16; ++i) {
      s0[i] = exp2f(fmaf(s0[i], CSC, nm2));
      s1[i] = exp2f(fmaf(s1[i], CSC, nm2));
    }
    float ts[16];
#pragma unroll
    for (int i = 0; i < 16; ++i) ts[i] = s0[i] + s1[i];
#pragma unroll
    for (int st = 8; st >= 1; st >>= 1)
#pragma unroll
      for (int i = 0; i < 8; ++i)
        if (i < st) ts[i] += ts[i + st];
    l_own += ts[0];

    // ---- P fragments: thanks to V column-permutation, frag[ks] = acc elems [8*(ks&1)..+7] of s_{ks>>1}
    union U8 { unsigned u[4]; bf16x8 v; };
    bf16x8 pf[4];
#define MK_PF(DST, SS, R0)                                                        \
    { U8 tt;                                                                      \
      asm("v_cvt_pk_bf16_f32 %0,%1,%2" : "=v"(tt.u[0]) : "v"(SS[R0+0]), "v"(SS[R0+1])); \
      asm("v_cvt_pk_bf16_f32 %0,%1,%2" : "=v"(tt.u[1]) : "v"(SS[R0+2]), "v"(SS[R0+3])); \
      asm("v_cvt_pk_bf16_f32 %0,%1,%2" : "=v"(tt.u[2]) : "v"(SS[R0+4]), "v"(SS[R0+5])); \
      asm("v_cvt_pk_bf16_f32 %0,%1,%2" : "=v"(tt.u[3]) : "v"(SS[R0+6]), "v"(SS[R0+7])); \
      DST = tt.v; }
    MK_PF(pf[0], s0, 0); MK_PF(pf[1], s0, 8);
    MK_PF(pf[2], s1, 0); MK_PF(pf[3], s1, 8);
#undef MK_PF

    // ---- PV: of = V^T(permuted cols) @ P
#pragma unroll
    for (int ks = 0; ks < 4; ++ks) {
      bf16x8 vf = ld_frag(curV + q31 * 128 + ((ks * 32 + coff) ^ swb));
      of0 = __builtin_amdgcn_mfma_f32_32x32x16_bf16(vf, pf[ks], of0, 0, 0, 0);
    }
#pragma unroll
    for (int ks = 0; ks < 4; ++ks) {
      bf16x8 vf = ld_frag(curV + (32 + q31) * 128 + ((ks * 32 + coff) ^ swb));
      of1 = __builtin_amdgcn_mfma_f32_32x32x16_bf16(vf, pf[ks], of1, 0, 0, 0);
    }

    if (kv < S / 64 - 1) { __syncthreads(); cur ^= 1; }
  }

  // ---- epilogue: combine l with partner lane, normalize, write
  float l_full = l_own + __shfl_xor(l_own, 32, 64);
  float inv = 1.f / l_full;
  int q = qbase + q31;
  u16* orow = Ob + (size_t)(b * S + q) * D + h * 64;
#pragma unroll
  for (int g = 0; g < 4; ++g) {
    ushort4 o0, o1;
    o0.x = f2bf(of0[g * 4 + 0] * inv); o0.y = f2bf(of0[g * 4 + 1] * inv);
    o0.z = f2bf(of0[g * 4 + 2] * inv); o0.w = f2bf(of0[g * 4 + 3] * inv);
    o1.x = f2bf(of1[g * 4 + 0] * inv); o1.y = f2bf(of1[g * 4 + 1] * inv);
    o1.z = f2bf(of1[g * 4 + 2] * inv); o1.w = f2bf(of1[g * 4 + 3] * inv);
    int hd0 = g * 8 + hi * 4;
    *(ushort4*)(orow + hd0) = o0;
    *(ushort4*)(orow + 32 + hd0) = o1;
  }
}

extern "C" void kernel_launch(void* const* d_in, const int* in_sizes, int n_in,
                              void* d_out, int out_size, void* d_ws, size_t ws_size,
                              hipStream_t stream) {
  const float* x      = (const float*)d_in[0];
  const float* qkv_w  = (const float*)d_in[1];
  const float* qkv_b  = (const float*)d_in[2];
  const float* proj_w = (const float*)d_in[3];
  const float* proj_b = (const float*)d_in[4];
  float* out = (float*)d_out;

  u16* ws  = (u16*)d_ws;
  u16* xb  = ws;                       // 8192*768
  u16* wt  = xb + 8192 * 768;          // 2304*768
  u16* pwt = wt + 2304 * 768;          // 768*768
  u16* Qb  = pwt + 768 * 768;          // 24*4096*64  [bh][S][64]
  u16* Kb  = Qb + 24 * 4096 * 64;      // [bh][S][64]
  u16* Vt  = Kb + 24 * 4096 * 64;      // [bh][64][S] (V transposed, cols bit2<->3 permuted)
  u16* Ob  = Vt + 24 * 4096 * 64;      // 8192*768

  k_f32_to_bf16<<<6144, 256, 0, stream>>>(x, xb, 8192 * 768 / 4);
  k_transpose_bf16<<<dim3(72, 24), dim3(32, 8), 0, stream>>>(qkv_w, wt, 768, 2304);
  k_transpose_bf16<<<dim3(24, 24), dim3(32, 8), 0, stream>>>(proj_w, pwt, 768, 768);
  k_gemm_qkv<<<dim3(18, 64), 256, 0, stream>>>(xb, wt, qkv_b, Qb, Kb, Vt);
  k_attn<<<768, 256, 0, stream>>>(Qb, Kb, Vt, Ob);
  k_gemm_proj<<<dim3(6, 64), 256, 0, stream>>>(Ob, pwt, proj_b, out);
}

// Round 5
// 241.839 us; speedup vs baseline: 1.7785x; 1.1944x over previous
//
#include <hip/hip_runtime.h>

typedef unsigned short u16;
typedef __attribute__((ext_vector_type(8))) short bf16x8;
typedef __attribute__((ext_vector_type(4))) float f32x4;
typedef __attribute__((ext_vector_type(16))) float f32x16;

__device__ __forceinline__ u16 f2bf(float f) {
  union { float f; unsigned u; } v; v.f = f;
  unsigned r = v.u + 0x7fffu + ((v.u >> 16) & 1u);
  return (u16)(r >> 16);
}
__device__ __forceinline__ float bf2f(u16 h) {
  union { unsigned u; float f; } v; v.u = ((unsigned)h) << 16;
  return v.f;
}

__device__ __forceinline__ bf16x8 ld_frag(const char* p) {
  union { uint4 u; bf16x8 v; } t;
  t.u = *(const uint4*)p;
  return t.v;
}
__device__ __forceinline__ float max3f(float a, float b, float c) {
  return fmaxf(fmaxf(a, b), c);   // fuses to v_max3_f32
}

// ---------------- fp32 -> bf16 convert (vectorized) ----------------
__global__ __launch_bounds__(256) void k_f32_to_bf16(const float* __restrict__ in,
                                                     u16* __restrict__ out, int n4) {
  int i = blockIdx.x * 256 + threadIdx.x;
  if (i < n4) {
    float4 v = ((const float4*)in)[i];
    ushort4 o; o.x = f2bf(v.x); o.y = f2bf(v.y); o.z = f2bf(v.z); o.w = f2bf(v.w);
    ((ushort4*)out)[i] = o;
  }
}

// ---------------- fp32 [R][C] -> bf16 [C][R] transpose ----------------
__global__ __launch_bounds__(256) void k_transpose_bf16(const float* __restrict__ in,
                                                        u16* __restrict__ out,
                                                        int R, int C) {
  __shared__ float tile[32][33];
  int bx = blockIdx.x * 32;
  int by = blockIdx.y * 32;
  int tx = threadIdx.x, ty = threadIdx.y;  // (32, 8)
#pragma unroll
  for (int j = 0; j < 32; j += 8)
    tile[ty + j][tx] = in[(size_t)(by + ty + j) * C + bx + tx];
  __syncthreads();
#pragma unroll
  for (int j = 0; j < 32; j += 8)
    out[(size_t)(bx + ty + j) * R + by + tx] = f2bf(tile[tx][ty + j]);
}

#define GAS(p) ((const __attribute__((address_space(1))) void*)(p))
#define LAS(p) ((__attribute__((address_space(3))) void*)(p))

// ---------------- QKV GEMM: [8192,768] x [768,2304] + bias, scatter Q/K row-major, V transposed+col-permuted ----------------
__global__ __launch_bounds__(256) void k_gemm_qkv(
    const u16* __restrict__ A,   // xb [8192][768]
    const u16* __restrict__ Bt,  // wt  [2304][768]
    const float* __restrict__ bias,
    u16* __restrict__ Qb, u16* __restrict__ Kb, u16* __restrict__ Vb) {
  const int K = 768;
  __shared__ u16 Al[128 * 64];
  __shared__ u16 Bl[128 * 64];
  int tn0 = blockIdx.x * 128, tm0 = blockIdx.y * 128;
  int tid = threadIdx.x, w = tid >> 6, lane = tid & 63;
  int l16 = lane & 15, lg = lane >> 4;
  int wm = (w >> 1) * 64, wn = (w & 1) * 64;
  f32x4 acc[4][4];
#pragma unroll
  for (int fm = 0; fm < 4; ++fm)
#pragma unroll
    for (int fn = 0; fn < 4; ++fn) acc[fm][fn] = (f32x4){0.f, 0.f, 0.f, 0.f};
  int srow = w * 32 + (lane >> 3);
  int scol = (lane & 7) * 8;
  for (int k0 = 0; k0 < K; k0 += 64) {
#pragma unroll
    for (int i = 0; i < 4; ++i) {
      __builtin_amdgcn_global_load_lds(GAS(A + (size_t)(tm0 + srow + i * 8) * K + k0 + scol),
                                       LAS((char*)Al + w * 4096 + i * 1024 + lane * 16), 16, 0, 0);
      __builtin_amdgcn_global_load_lds(GAS(Bt + (size_t)(tn0 + srow + i * 8) * K + k0 + scol),
                                       LAS((char*)Bl + w * 4096 + i * 1024 + lane * 16), 16, 0, 0);
    }
    __syncthreads();
#pragma unroll
    for (int ks = 0; ks < 2; ++ks) {
      bf16x8 af[4], bv[4];
#pragma unroll
      for (int f = 0; f < 4; ++f)
        af[f] = *(const bf16x8*)&Al[(wm + f * 16 + l16) * 64 + lg * 8 + ks * 32];
#pragma unroll
      for (int f = 0; f < 4; ++f)
        bv[f] = *(const bf16x8*)&Bl[(wn + f * 16 + l16) * 64 + lg * 8 + ks * 32];
#pragma unroll
      for (int fm = 0; fm < 4; ++fm)
#pragma unroll
        for (int fn = 0; fn < 4; ++fn)
          acc[fm][fn] = __builtin_amdgcn_mfma_f32_16x16x32_bf16(af[fm], bv[fn], acc[fm][fn], 0, 0, 0);
    }
    __syncthreads();
  }
  int part = tn0 / 768;  // block-uniform (768 = 6*128)
  u16* dst = part == 0 ? Qb : (part == 1 ? Kb : Vb);
#pragma unroll
  for (int fn = 0; fn < 4; ++fn) {
    int nn = tn0 + wn + fn * 16 + l16;
    float bvs = bias[nn];
    int np = nn - part * 768;
    int hh = np >> 6, hd = np & 63;
#pragma unroll
    for (int fm = 0; fm < 4; ++fm) {
#pragma unroll
      for (int r = 0; r < 4; ++r) {
        int m = tm0 + wm + fm * 16 + lg * 4 + r;
        int bb = m >> 12, s = m & 4095;
        size_t idx;
        if (part == 2) {
          // V^T [bh][hd][S], sk columns permuted: swap bits 2<->3 of s
          int sp = (s & ~12) | ((s & 8) >> 1) | ((s & 4) << 1);
          idx = (((size_t)(bb * 12 + hh)) * 64 + hd) * 4096 + sp;
        } else {
          idx = (((size_t)(bb * 12 + hh)) * 4096 + s) * 64 + hd;  // Q/K [bh][S][64]
        }
        dst[idx] = f2bf(acc[fm][fn][r] + bvs);
      }
    }
  }
}

// ---------------- proj GEMM: [8192,768] x [768,768] + bias -> fp32 out ----------------
__global__ __launch_bounds__(256) void k_gemm_proj(
    const u16* __restrict__ A,   // Ob [8192][768]
    const u16* __restrict__ Bt,  // pwt [768][768]
    const float* __restrict__ bias, float* __restrict__ out) {
  const int K = 768;
  __shared__ u16 Al[128 * 64];
  __shared__ u16 Bl[128 * 64];
  int tn0 = blockIdx.x * 128, tm0 = blockIdx.y * 128;
  int tid = threadIdx.x, w = tid >> 6, lane = tid & 63;
  int l16 = lane & 15, lg = lane >> 4;
  int wm = (w >> 1) * 64, wn = (w & 1) * 64;
  f32x4 acc[4][4];
#pragma unroll
  for (int fm = 0; fm < 4; ++fm)
#pragma unroll
    for (int fn = 0; fn < 4; ++fn) acc[fm][fn] = (f32x4){0.f, 0.f, 0.f, 0.f};
  int srow = w * 32 + (lane >> 3);
  int scol = (lane & 7) * 8;
  for (int k0 = 0; k0 < K; k0 += 64) {
#pragma unroll
    for (int i = 0; i < 4; ++i) {
      __builtin_amdgcn_global_load_lds(GAS(A + (size_t)(tm0 + srow + i * 8) * K + k0 + scol),
                                       LAS((char*)Al + w * 4096 + i * 1024 + lane * 16), 16, 0, 0);
      __builtin_amdgcn_global_load_lds(GAS(Bt + (size_t)(tn0 + srow + i * 8) * K + k0 + scol),
                                       LAS((char*)Bl + w * 4096 + i * 1024 + lane * 16), 16, 0, 0);
    }
    __syncthreads();
#pragma unroll
    for (int ks = 0; ks < 2; ++ks) {
      bf16x8 af[4], bv[4];
#pragma unroll
      for (int f = 0; f < 4; ++f)
        af[f] = *(const bf16x8*)&Al[(wm + f * 16 + l16) * 64 + lg * 8 + ks * 32];
#pragma unroll
      for (int f = 0; f < 4; ++f)
        bv[f] = *(const bf16x8*)&Bl[(wn + f * 16 + l16) * 64 + lg * 8 + ks * 32];
#pragma unroll
      for (int fm = 0; fm < 4; ++fm)
#pragma unroll
        for (int fn = 0; fn < 4; ++fn)
          acc[fm][fn] = __builtin_amdgcn_mfma_f32_16x16x32_bf16(af[fm], bv[fn], acc[fm][fn], 0, 0, 0);
    }
    __syncthreads();
  }
#pragma unroll
  for (int fn = 0; fn < 4; ++fn) {
    int nn = tn0 + wn + fn * 16 + l16;
    float bvs = bias[nn];
#pragma unroll
    for (int fm = 0; fm < 4; ++fm) {
#pragma unroll
      for (int r = 0; r < 4; ++r) {
        int m = tm0 + wm + fm * 16 + lg * 4 + r;
        out[(size_t)m * 768 + nn] = acc[fm][fn][r] + bvs;
      }
    }
  }
}

// ---------------- flash attention, 32x32 MFMA, in-register P, native exp2 ----------------
__global__ __launch_bounds__(256, 3) void k_attn(const u16* __restrict__ Qb,
                                                 const u16* __restrict__ Kb,
                                                 const u16* __restrict__ Vtg,
                                                 u16* __restrict__ Ob) {
  const int S = 4096, NH = 12, D = 768;
  __shared__ u16 Kl[2][64 * 64];     // 0: bytes 0..8191, 1: 8192..16383
  __shared__ u16 Vl[2][64 * 64];     // 0: 16384.., 1: 24576..

  int bid0 = blockIdx.x;
  int bid = (bid0 & 7) * 96 + (bid0 >> 3);   // XCD-bijective swizzle (768 % 8 == 0)
  int qp = bid & 31;
  int bh = bid >> 5;
  int b = bh / NH, h = bh % NH;
  const u16* Qh = Qb + (size_t)bh * S * 64;
  const char* Khc = (const char*)(Kb + (size_t)bh * S * 64);
  const char* Vhc = (const char*)(Vtg + (size_t)bh * 64 * S);

  int tid = threadIdx.x, w = tid >> 6, lane = tid & 63;
  int q31 = lane & 31, hi = lane >> 5;
  int swb = (q31 & 7) << 4;
  int coff = (hi << 4);

  // per-lane LDS read offsets (within a 64x64 tile); +4096 bytes for rows 32..63
  unsigned xoff[4];
#pragma unroll
  for (int ks = 0; ks < 4; ++ks)
    xoff[ks] = (unsigned)(q31 * 128 + ((ks * 32 + coff) ^ swb));

  // staging: wave w stages rows w*16..w*16+15, pre-swizzled source chunk
  int r8 = lane >> 3;
  int chs = (lane & 7) ^ r8;
  const char* kSrc = Khc + (size_t)(w * 16 + r8) * 128 + chs * 16;
  const char* vSrc = Vhc + (size_t)(w * 16 + r8) * 8192 + chs * 16;
  char* kDst0 = (char*)&Kl[0][0] + w * 2048 + lane * 16;
  char* vDst0 = (char*)&Vl[0][0] + w * 2048 + lane * 16;

  auto STAGE = [&](int bufi, int kv) {
#pragma unroll
    for (int qq = 0; qq < 2; ++qq) {
      __builtin_amdgcn_global_load_lds(GAS(kSrc + (size_t)kv * 8192 + qq * 1024),
                                       LAS(kDst0 + bufi * 8192 + qq * 1024), 16, 0, 0);
      __builtin_amdgcn_global_load_lds(GAS(vSrc + (size_t)qq * 65536 + (size_t)kv * 128),
                                       LAS(vDst0 + bufi * 8192 + qq * 1024), 16, 0, 0);
    }
  };

  // Q fragments (B-operand)
  int qbase = qp * 128 + w * 32;
  const u16* qrow = Qh + (size_t)(qbase + q31) * 64;
  bf16x8 qf[4];
#pragma unroll
  for (int ks = 0; ks < 4; ++ks)
    qf[ks] = *(const bf16x8*)(qrow + ks * 16 + hi * 8);

  f32x16 of0, of1;
#pragma unroll
  for (int i = 0; i < 16; ++i) { of0[i] = 0.f; of1[i] = 0.f; }
  float m2 = -1e30f, l_own = 0.f;
  const float CSC = 0.18033688011112042f;  // log2(e) / 8

  auto TILE = [&](const char* KB, const char* VB) {
    // QK^T
    f32x16 s0, s1;
#pragma unroll
    for (int i = 0; i < 16; ++i) { s0[i] = 0.f; s1[i] = 0.f; }
#pragma unroll
    for (int ks = 0; ks < 4; ++ks) {
      bf16x8 kf = ld_frag(KB + xoff[ks]);
      s0 = __builtin_amdgcn_mfma_f32_32x32x16_bf16(kf, qf[ks], s0, 0, 0, 0);
    }
#pragma unroll
    for (int ks = 0; ks < 4; ++ks) {
      bf16x8 kf = ld_frag(KB + 4096 + xoff[ks]);
      s1 = __builtin_amdgcn_mfma_f32_32x32x16_bf16(kf, qf[ks], s1, 0, 0, 0);
    }
    // softmax (q-row q31); max via max3 tree, native exp2
    float t[11];
#pragma unroll
    for (int i = 0; i < 10; ++i) t[i] = max3f(fmaxf(s0[i], s1[i]),
                                              fmaxf(s0[i + 6] , s1[i + 6] ) * 0.f + fmaxf(s0[(i*0)], s0[(i*0)]) * 0.f - 1e30f,
                                              -1e30f);
    // (simple, reliable tree instead of the clever-but-buggy line above)
#pragma unroll
    for (int i = 0; i < 8; ++i) t[i] = fmaxf(fmaxf(s0[i], s0[i + 8]), fmaxf(s1[i], s1[i + 8]));
    float m4a = max3f(t[0], t[1], t[2]), m4b = max3f(t[3], t[4], t[5]);
    float mx = max3f(fmaxf(m4a, m4b), t[6], t[7]);
    mx = fmaxf(mx, __shfl_xor(mx, 32, 64));
    float mx2 = mx * CSC;
    if (mx2 > m2 + 8.f) {            // defer-max (THR=8 in log2 domain)
      float scl = __builtin_amdgcn_exp2f(m2 - mx2);
      m2 = mx2; l_own *= scl;
#pragma unroll
      for (int i = 0; i < 16; ++i) { of0[i] *= scl; of1[i] *= scl; }
    }
    float nm2 = -m2;
#pragma unroll
    for (int i = 0; i < 16; ++i) {
      s0[i] = __builtin_amdgcn_exp2f(fmaf(s0[i], CSC, nm2));
      s1[i] = __builtin_amdgcn_exp2f(fmaf(s1[i], CSC, nm2));
    }
    float ts[8];
#pragma unroll
    for (int i = 0; i < 8; ++i) ts[i] = (s0[i] + s0[i + 8]) + (s1[i] + s1[i + 8]);
#pragma unroll
    for (int st = 4; st >= 1; st >>= 1)
#pragma unroll
      for (int i = 0; i < 4; ++i)
        if (i < st) ts[i] += ts[i + st];
    l_own += ts[0];
    // P fragments (V col-permutation makes acc order = fragment order)
    union U8 { unsigned u[4]; bf16x8 v; };
    bf16x8 pf[4];
#define MK_PF(DST, SS, R0)                                                        \
    { U8 tt;                                                                      \
      asm("v_cvt_pk_bf16_f32 %0,%1,%2" : "=v"(tt.u[0]) : "v"(SS[R0+0]), "v"(SS[R0+1])); \
      asm("v_cvt_pk_bf16_f32 %0,%1,%2" : "=v"(tt.u[1]) : "v"(SS[R0+2]), "v"(SS[R0+3])); \
      asm("v_cvt_pk_bf16_f32 %0,%1,%2" : "=v"(tt.u[2]) : "v"(SS[R0+4]), "v"(SS[R0+5])); \
      asm("v_cvt_pk_bf16_f32 %0,%1,%2" : "=v"(tt.u[3]) : "v"(SS[R0+6]), "v"(SS[R0+7])); \
      DST = tt.v; }
    MK_PF(pf[0], s0, 0); MK_PF(pf[1], s0, 8);
    MK_PF(pf[2], s1, 0); MK_PF(pf[3], s1, 8);
#undef MK_PF
    // PV
#pragma unroll
    for (int ks = 0; ks < 4; ++ks) {
      bf16x8 vf = ld_frag(VB + xoff[ks]);
      of0 = __builtin_amdgcn_mfma_f32_32x32x16_bf16(vf, pf[ks], of0, 0, 0, 0);
    }
#pragma unroll
    for (int ks = 0; ks < 4; ++ks) {
      bf16x8 vf = ld_frag(VB + 4096 + xoff[ks]);
      of1 = __builtin_amdgcn_mfma_f32_32x32x16_bf16(vf, pf[ks], of1, 0, 0, 0);
    }
  };

  const char* K0 = (const char*)&Kl[0][0];
  const char* K1 = (const char*)&Kl[1][0];
  const char* V0 = (const char*)&Vl[0][0];
  const char* V1 = (const char*)&Vl[1][0];

  STAGE(0, 0);
  __syncthreads();

#pragma unroll 1
  for (int kv = 0; kv < S / 64; kv += 2) {
    STAGE(1, kv + 1);
    TILE(K0, V0);
    __syncthreads();
    if (kv + 2 < S / 64) STAGE(0, kv + 2);
    TILE(K1, V1);
    if (kv + 2 < S / 64) __syncthreads();
  }

  // epilogue
  float l_full = l_own + __shfl_xor(l_own, 32, 64);
  float inv = 1.f / l_full;
  int q = qbase + q31;
  u16* orow = Ob + (size_t)(b * S + q) * D + h * 64;
#pragma unroll
  for (int g = 0; g < 4; ++g) {
    ushort4 o0, o1;
    o0.x = f2bf(of0[g * 4 + 0] * inv); o0.y = f2bf(of0[g * 4 + 1] * inv);
    o0.z = f2bf(of0[g * 4 + 2] * inv); o0.w = f2bf(of0[g * 4 + 3] * inv);
    o1.x = f2bf(of1[g * 4 + 0] * inv); o1.y = f2bf(of1[g * 4 + 1] * inv);
    o1.z = f2bf(of1[g * 4 + 2] * inv); o1.w = f2bf(of1[g * 4 + 3] * inv);
    int hd0 = g * 8 + hi * 4;
    *(ushort4*)(orow + hd0) = o0;
    *(ushort4*)(orow + 32 + hd0) = o1;
  }
}

extern "C" void kernel_launch(void* const* d_in, const int* in_sizes, int n_in,
                              void* d_out, int out_size, void* d_ws, size_t ws_size,
                              hipStream_t stream) {
  const float* x      = (const float*)d_in[0];
  const float* qkv_w  = (const float*)d_in[1];
  const float* qkv_b  = (const float*)d_in[2];
  const float* proj_w = (const float*)d_in[3];
  const float* proj_b = (const float*)d_in[4];
  float* out = (float*)d_out;

  u16* ws  = (u16*)d_ws;
  u16* xb  = ws;                       // 8192*768
  u16* wt  = xb + 8192 * 768;          // 2304*768
  u16* pwt = wt + 2304 * 768;          // 768*768
  u16* Qb  = pwt + 768 * 768;          // 24*4096*64  [bh][S][64]
  u16* Kb  = Qb + 24 * 4096 * 64;      // [bh][S][64]
  u16* Vt  = Kb + 24 * 4096 * 64;      // [bh][64][S] (V transposed, cols bit2<->3 permuted)
  u16* Ob  = Vt + 24 * 4096 * 64;      // 8192*768

  k_f32_to_bf16<<<6144, 256, 0, stream>>>(x, xb, 8192 * 768 / 4);
  k_transpose_bf16<<<dim3(72, 24), dim3(32, 8), 0, stream>>>(qkv_w, wt, 768, 2304);
  k_transpose_bf16<<<dim3(24, 24), dim3(32, 8), 0, stream>>>(proj_w, pwt, 768, 768);
  k_gemm_qkv<<<dim3(18, 64), 256, 0, stream>>>(xb, wt, qkv_b, Qb, Kb, Vt);
  k_attn<<<768, 256, 0, stream>>>(Qb, Kb, Vt, Ob);
  k_gemm_proj<<<dim3(6, 64), 256, 0, stream>>>(Ob, pwt, proj_b, out);
}